// Round 14
// baseline (395.684 us; speedup 1.0000x reference)
//
#include <hip/hip_runtime.h>
#include <hip/hip_bf16.h>

#define B_ 32
#define T_ 2048
#define D_ 1024
#define N_ 1024
#define M_ (B_*T_)

#define BM 64
#define BN 128
#define BK 64
#define NTSPLIT 2                  // two disjoint score-partial buffers, summed in k3
#define NTP (N_ / BN / NTSPLIT)    // 4 nt-passes per block
#define NSTEP (NTP * (D_ / BK))    // 64 flat steps (nt,kt)

typedef short bf16x8 __attribute__((ext_vector_type(8)));
typedef float f32x4 __attribute__((ext_vector_type(4)));
typedef unsigned short us4 __attribute__((ext_vector_type(4)));

__device__ __forceinline__ unsigned short bf16_rn(float x) {
    unsigned u = __float_as_uint(x);
    u += 0x7FFFu + ((u >> 16) & 1u);
    return (unsigned short)(u >> 16);
}

__device__ __forceinline__ void gload_lds16(const void* g, void* l) {
    __builtin_amdgcn_global_load_lds(
        (__attribute__((address_space(1))) void*)(g),
        (__attribute__((address_space(3))) void*)(l), 16, 0, 0);
}

// K0: W2 [D][N] fp32 -> W2T bf16 (RTN) [N][D]
__global__ void k0_w2t(const float* __restrict__ W2,
                       unsigned short* __restrict__ Th) {
    __shared__ float tile[32][33];
    int n0 = blockIdx.x * 32, d0 = blockIdx.y * 32;
    int tx = threadIdx.x & 31, ty = threadIdx.x >> 5; // 32 x 8
    #pragma unroll
    for (int i = 0; i < 4; i++) {
        int d = d0 + ty + i * 8;
        tile[ty + i * 8][tx] = W2[d * N_ + n0 + tx];
    }
    __syncthreads();
    #pragma unroll
    for (int i = 0; i < 4; i++) {
        int n = n0 + ty + i * 8;
        Th[n * D_ + d0 + tx] = bf16_rn(tile[tx][ty + i * 8]);
    }
}

// K0v: values [M][D] fp32 -> Av bf16 (RTN), vectorized grid-stride
__global__ void k0_vals(const float* __restrict__ v,
                        unsigned short* __restrict__ o) {
    size_t i = ((size_t)blockIdx.x * 256 + threadIdx.x) * 8;
    const size_t stride = (size_t)gridDim.x * 256 * 8;
    for (; i < (size_t)M_ * D_; i += stride) {
        float4 a = *(const float4*)(v + i);
        float4 b = *(const float4*)(v + i + 4);
        us4 h0, h1;
        h0[0] = bf16_rn(a.x); h0[1] = bf16_rn(a.y);
        h0[2] = bf16_rn(a.z); h0[3] = bf16_rn(a.w);
        h1[0] = bf16_rn(b.x); h1[1] = bf16_rn(b.y);
        h1[2] = bf16_rn(b.z); h1[3] = bf16_rn(b.w);
        *(us4*)(o + i) = h0;
        *(us4*)(o + i + 4) = h1;
    }
}

// K1: q_proj[b][n] = query[b]@W1[:,n] + b1[n]   (fp32)
__global__ void k1_qproj(const float* __restrict__ query,
                         const float* __restrict__ W1,
                         const float* __restrict__ b1,
                         float* __restrict__ qp) {
    int b = blockIdx.x;
    int n = blockIdx.y * 256 + threadIdx.x;
    const float* q = query + b * D_;
    const float* w = W1 + n;
    float s = 0.f;
    #pragma unroll 8
    for (int d = 0; d < D_; d++) s += q[d] * w[d * N_];
    qp[b * N_ + n] = s + b1[n];
}

// k2 staging for flat step u: B 4 + A 2 gload_lds per thread (R11-verified
// mappings, XOR-8 pre-swizzled sources, wave-uniform LDS dests).
__device__ __forceinline__ void k2_stage(int u, unsigned short* sa, unsigned short* sb,
                                         int m0, int nt0, int wid, int b_rl, int b_j,
                                         const unsigned short* __restrict__ Av,
                                         const unsigned short* __restrict__ W2Th) {
    const int nt = nt0 + (u >> 4);
    const int k0 = (u & 15) * BK;
    #pragma unroll
    for (int i = 0; i < 4; i++) {
        int r = wid * 32 + i * 8 + b_rl;
        int jj = b_j ^ (r & 7);
        size_t soff = (size_t)(nt * BN + r) * D_ + k0 + jj * 8;
        gload_lds16(W2Th + soff, &sb[(wid * 32 + i * 8) * 64]);
    }
    #pragma unroll
    for (int i = 0; i < 2; i++) {
        int r = wid * 16 + i * 8 + b_rl;
        int jj = b_j ^ (r & 7);
        size_t soff = (size_t)(m0 + r) * D_ + k0 + jj * 8;
        gload_lds16(Av + soff, &sa[(wid * 16 + i * 8) * 64]);
    }
}

// K2: fused score GEMM partial. R11-verified geometry/mappings (64x128x64,
// 4 waves 2Mx2N, acc[2][4]=32 AGPR, Av bf16 staging) with T3-minimum
// double-buffered SINGLE-barrier schedule: stage(u+1 -> buf^1) issued
// BEFORE compute(u, buf); __syncthreads() at step end drains loads that
// have been in flight under the compute (not just-issued). Race-free:
// barrier guarantees all waves' next-tile loads landed AND all finished
// reading buf[cur] before it is overwritten (same argument as R2, one
// barrier). Disjoint NTSPLIT partial output (no atomics); bV dropped.
__global__ __launch_bounds__(256, 2) void k2_score(
    const unsigned short* __restrict__ Av,
    const unsigned short* __restrict__ W2Th,
    const float* __restrict__ qp,
    const float* __restrict__ b2,
    const float* __restrict__ V,
    float* __restrict__ scorep) {
    __shared__ unsigned short sA[2][BM * BK];   // 2 x 8 KB
    __shared__ unsigned short sB[2][BN * BK];   // 2 x 16 KB
    __shared__ float red[2 * BM];

    const int tid = threadIdx.x;
    const int lane = tid & 63;
    const int wid = tid >> 6;
    const int wm = wid >> 1, wn = wid & 1;    // wave tile 32x64
    const int g = lane >> 4, c16 = lane & 15;

    // XCD-pairing swizzle (R11-verified): bijective rotation on [0,2048)
    const int bid = blockIdx.x;
    const int wgid = ((bid & 7) << 8) | (bid >> 3);
    const int m0 = (wgid >> 1) * BM;
    const int b = m0 >> 11; // m0 / T_
    const int half = wgid & 1;
    const int nt0 = half * NTP;

    const int b_rl = lane >> 3;
    const int b_j = lane & 7;

    float rowpart[8];
    #pragma unroll
    for (int i = 0; i < 8; i++) rowpart[i] = 0.f;

    f32x4 acc[2][4];
    #pragma unroll
    for (int mi = 0; mi < 2; mi++)
        #pragma unroll
        for (int ni = 0; ni < 4; ni++) {
            f32x4 z = {0.f, 0.f, 0.f, 0.f};
            acc[mi][ni] = z;
        }

    // prologue: stage step 0 into buffer 0
    k2_stage(0, sA[0], sB[0], m0, nt0, wid, b_rl, b_j, Av, W2Th);
    __syncthreads();

    for (int u = 0; u < NSTEP; ++u) {
        const int cur = u & 1;

        // issue next step's staging first (overlaps with compute below)
        if (u + 1 < NSTEP)
            k2_stage(u + 1, sA[cur ^ 1], sB[cur ^ 1], m0, nt0, wid, b_rl, b_j, Av, W2Th);

        // compute on current buffer
        #pragma unroll
        for (int s = 0; s < 2; s++) {
            bf16x8 aH[2], bH[4];
            #pragma unroll
            for (int mi = 0; mi < 2; mi++) {
                int r = wm * 32 + mi * 16 + c16;
                int idx = r * 64 + (((s * 4 + g) ^ (r & 7)) << 3);
                aH[mi] = *(const bf16x8*)&sA[cur][idx];
            }
            #pragma unroll
            for (int ni = 0; ni < 4; ni++) {
                int r = wn * 64 + ni * 16 + c16;
                int idx = r * 64 + (((s * 4 + g) ^ (r & 7)) << 3);
                bH[ni] = *(const bf16x8*)&sB[cur][idx];
            }
            #pragma unroll
            for (int mi = 0; mi < 2; mi++)
                #pragma unroll
                for (int ni = 0; ni < 4; ni++)
                    acc[mi][ni] = __builtin_amdgcn_mfma_f32_16x16x32_bf16(aH[mi], bH[ni], acc[mi][ni], 0, 0, 0);
        }

        // nt-pass epilogue: fold acc into rowpart via tanh, reset acc
        if ((u & 15) == 15) {
            int nt = nt0 + (u >> 4);
            #pragma unroll
            for (int ni = 0; ni < 4; ni++) {
                int n = nt * BN + wn * 64 + ni * 16 + c16;
                float qv = qp[b * N_ + n] + b2[n];
                float Vv = V[n];
                #pragma unroll
                for (int mi = 0; mi < 2; mi++)
                    #pragma unroll
                    for (int r = 0; r < 4; r++)
                        rowpart[mi * 4 + r] += tanhf(acc[mi][ni][r] + qv) * Vv;
            }
            #pragma unroll
            for (int mi = 0; mi < 2; mi++)
                #pragma unroll
                for (int ni = 0; ni < 4; ni++) {
                    f32x4 z = {0.f, 0.f, 0.f, 0.f};
                    acc[mi][ni] = z;
                }
        }

        __syncthreads();  // drains my stage loads (in flight under compute); flip
    }

    // reduce across the 16 n-lanes of each group
    #pragma unroll
    for (int i = 0; i < 8; i++) {
        float v = rowpart[i];
        v += __shfl_xor(v, 1);
        v += __shfl_xor(v, 2);
        v += __shfl_xor(v, 4);
        v += __shfl_xor(v, 8);
        rowpart[i] = v;
    }
    if (c16 == 0) {
        #pragma unroll
        for (int mi = 0; mi < 2; mi++)
            #pragma unroll
            for (int r = 0; r < 4; r++)
                red[wn * BM + wm * 32 + mi * 16 + g * 4 + r] = rowpart[mi * 4 + r];
    }
    __syncthreads();
    if (tid < BM) {
        // plain store to this half's disjoint partial buffer (no atomics)
        scorep[(size_t)half * M_ + m0 + tid] = red[tid] + red[BM + tid];
    }
}

// K3: softmax over T per batch: sums the two score partials, softmaxes,
// writes weights (d_out region written only here).
__global__ void k3_softmax(const float* __restrict__ sp,
                           float* __restrict__ sw) {
    int b = blockIdx.x;
    const float* r0 = sp + b * T_;
    const float* r1 = sp + M_ + b * T_;
    float* row = sw + b * T_;
    int tid = threadIdx.x;
    float v[8];
    float lmax = -1e30f;
    #pragma unroll
    for (int i = 0; i < 8; i++) {
        int idx = tid + i * 256;
        v[i] = r0[idx] + r1[idx];
        lmax = fmaxf(lmax, v[i]);
    }
    #pragma unroll
    for (int d = 1; d < 64; d <<= 1) lmax = fmaxf(lmax, __shfl_xor(lmax, d));
    __shared__ float sm[4], ss[4];
    if ((tid & 63) == 0) sm[tid >> 6] = lmax;
    __syncthreads();
    lmax = fmaxf(fmaxf(sm[0], sm[1]), fmaxf(sm[2], sm[3]));
    float lsum = 0.f;
    #pragma unroll
    for (int i = 0; i < 8; i++) {
        v[i] = expf(v[i] - lmax);
        lsum += v[i];
    }
    #pragma unroll
    for (int d = 1; d < 64; d <<= 1) lsum += __shfl_xor(lsum, d);
    if ((tid & 63) == 0) ss[tid >> 6] = lsum;
    __syncthreads();
    lsum = ss[0] + ss[1] + ss[2] + ss[3];
    float inv = 1.f / lsum;
    #pragma unroll
    for (int i = 0; i < 8; i++) row[tid + i * 256] = v[i] * inv;
}

// K4: context[b][d] += partial over t-slice, reading bf16 Av (half traffic).
// (atomic, ctx pre-zeroed)
__global__ void k4_context(const unsigned short* __restrict__ Av,
                           const float* __restrict__ w,
                           float* __restrict__ ctx) {
    int b = blockIdx.x;
    int dc = blockIdx.y;           // 8 chunks of 128 d
    int tc = blockIdx.z;           // 8 chunks of 256 t
    int d4 = threadIdx.x & 31;
    int th = threadIdx.x >> 5;     // 8 t-slices of 32
    const float* wrow = w + b * T_;
    int d = dc * 128 + d4 * 4;
    const unsigned short* vbase = Av + (size_t)b * T_ * D_ + d;
    float4 acc = {0.f, 0.f, 0.f, 0.f};
    int t0 = tc * 256 + th * 32;
    for (int t = t0; t < t0 + 32; t++) {
        float wt = wrow[t];
        us4 hv = *(const us4*)(vbase + (size_t)t * D_);
        acc.x += wt * __uint_as_float((unsigned)hv[0] << 16);
        acc.y += wt * __uint_as_float((unsigned)hv[1] << 16);
        acc.z += wt * __uint_as_float((unsigned)hv[2] << 16);
        acc.w += wt * __uint_as_float((unsigned)hv[3] << 16);
    }
    __shared__ float4 red4[256];
    red4[threadIdx.x] = acc;
    __syncthreads();
    if (th == 0) {
        float4 s = red4[d4];
        #pragma unroll
        for (int i = 1; i < 8; i++) {
            float4 o = red4[i * 32 + d4];
            s.x += o.x; s.y += o.y; s.z += o.z; s.w += o.w;
        }
        atomicAdd(&ctx[b * D_ + d + 0], s.x);
        atomicAdd(&ctx[b * D_ + d + 1], s.y);
        atomicAdd(&ctx[b * D_ + d + 2], s.z);
        atomicAdd(&ctx[b * D_ + d + 3], s.w);
    }
}

extern "C" void kernel_launch(void* const* d_in, const int* in_sizes, int n_in,
                              void* d_out, int out_size, void* d_ws, size_t ws_size,
                              hipStream_t stream) {
    const float* query  = (const float*)d_in[0];
    const float* values = (const float*)d_in[1];
    const float* W1     = (const float*)d_in[2];
    const float* b1     = (const float*)d_in[3];
    const float* W2     = (const float*)d_in[4];
    const float* b2     = (const float*)d_in[5];
    const float* V      = (const float*)d_in[6];
    // d_in[7] = bV: unused — softmax is shift-invariant, bV affects neither output.

    float* ctx = (float*)d_out;                 // [B, D]
    float* weights = (float*)d_out + B_ * D_;   // [B, T]: written by k3 only

    // ws: W2T (2 MB) | q_proj (128 KB) | score partials (2x512 KB) | Av bf16 (128 MB)
    size_t need = (size_t)N_ * D_ * sizeof(unsigned short)
                + (size_t)B_ * N_ * sizeof(float)
                + (size_t)NTSPLIT * M_ * sizeof(float)
                + (size_t)M_ * D_ * sizeof(unsigned short);
    if (ws_size < need) return;
    unsigned short* Th = (unsigned short*)d_ws;
    float* qp = (float*)(Th + (size_t)N_ * D_);
    float* scorep = qp + (size_t)B_ * N_;
    unsigned short* Av = (unsigned short*)(scorep + (size_t)NTSPLIT * M_);

    k0_w2t<<<dim3(N_ / 32, D_ / 32), 256, 0, stream>>>(W2, Th);
    k0_vals<<<2048, 256, 0, stream>>>(values, Av);
    k1_qproj<<<dim3(B_, N_ / 256), 256, 0, stream>>>(query, W1, b1, qp);
    k2_score<<<(M_ / BM) * NTSPLIT, 256, 0, stream>>>(Av, Th, qp, b2, V, scorep);
    k3_softmax<<<B_, 256, 0, stream>>>(scorep, weights);
    hipMemsetAsync(ctx, 0, (size_t)B_ * D_ * sizeof(float), stream);
    k4_context<<<dim3(B_, 8, 8), 256, 0, stream>>>(Av, weights, ctx);
}

// Round 15
// 346.957 us; speedup vs baseline: 1.1404x; 1.1404x over previous
//
#include <hip/hip_runtime.h>
#include <hip/hip_bf16.h>

#define B_ 32
#define T_ 2048
#define D_ 1024
#define N_ 1024
#define M_ (B_*T_)

#define BM 64
#define BN 128
#define BK 64
#define NTSPLIT 2                  // two disjoint score-partial buffers, summed in k3
#define NTP (N_ / BN / NTSPLIT)    // 4 nt-passes per block

typedef short bf16x8 __attribute__((ext_vector_type(8)));
typedef float f32x4 __attribute__((ext_vector_type(4)));
typedef unsigned short us4 __attribute__((ext_vector_type(4)));

__device__ __forceinline__ unsigned short bf16_rn(float x) {
    unsigned u = __float_as_uint(x);
    u += 0x7FFFu + ((u >> 16) & 1u);
    return (unsigned short)(u >> 16);
}

__device__ __forceinline__ void gload_lds16(const void* g, void* l) {
    __builtin_amdgcn_global_load_lds(
        (__attribute__((address_space(1))) void*)(g),
        (__attribute__((address_space(3))) void*)(l), 16, 0, 0);
}

// K_prep: fused prologue, block-range dispatch (one launch instead of three).
//   blocks [0,2048):    values fp32 -> Av bf16 (RTN)      [verified k0_vals body]
//   blocks [2048,3072): W2 [D][N] -> W2T bf16 [N][D]      [verified k0_w2t body]
//   blocks [3072,3200): qp[b][n] = query@W1 + b1          [verified k1 body]
// The 8 MB of w2t/qproj traffic hides inside the 402 MB conversion stream.
__global__ void k_prep(const float* __restrict__ values, unsigned short* __restrict__ Av,
                       const float* __restrict__ W2, unsigned short* __restrict__ Th,
                       const float* __restrict__ query, const float* __restrict__ W1,
                       const float* __restrict__ b1, float* __restrict__ qp) {
    __shared__ float tile[32][33];
    const int blk = blockIdx.x;
    const int tid = threadIdx.x;

    if (blk < 2048) {
        // --- values -> Av: 32768 contiguous elems per block, 16 iters of 8/thread
        size_t base = (size_t)blk * 32768 + (size_t)tid * 8;
        #pragma unroll 4
        for (int it = 0; it < 16; ++it) {
            size_t i = base + (size_t)it * 2048;
            float4 a = *(const float4*)(values + i);
            float4 b = *(const float4*)(values + i + 4);
            us4 h0, h1;
            h0[0] = bf16_rn(a.x); h0[1] = bf16_rn(a.y);
            h0[2] = bf16_rn(a.z); h0[3] = bf16_rn(a.w);
            h1[0] = bf16_rn(b.x); h1[1] = bf16_rn(b.y);
            h1[2] = bf16_rn(b.z); h1[3] = bf16_rn(b.w);
            *(us4*)(Av + i) = h0;
            *(us4*)(Av + i + 4) = h1;
        }
    } else if (blk < 3072) {
        // --- W2 -> W2T (32x32 tile transpose via LDS)
        int t = blk - 2048;
        int n0 = (t & 31) * 32, d0 = (t >> 5) * 32;
        int tx = tid & 31, ty = tid >> 5; // 32 x 8
        #pragma unroll
        for (int i = 0; i < 4; i++) {
            int d = d0 + ty + i * 8;
            tile[ty + i * 8][tx] = W2[d * N_ + n0 + tx];
        }
        __syncthreads();
        #pragma unroll
        for (int i = 0; i < 4; i++) {
            int n = n0 + ty + i * 8;
            Th[n * D_ + d0 + tx] = bf16_rn(tile[tx][ty + i * 8]);
        }
    } else {
        // --- q_proj
        int t = blk - 3072;           // 0..127
        int b = t & 31;
        int n = (t >> 5) * 256 + tid; // 4 n-chunks of 256
        const float* q = query + b * D_;
        const float* w = W1 + n;
        float s = 0.f;
        #pragma unroll 8
        for (int d = 0; d < D_; d++) s += q[d] * w[d * N_];
        qp[b * N_ + n] = s + b1[n];
    }
}

// K2: fused score GEMM partial — byte-for-byte the R11-measured kernel
// (205 us: 64x128x64 tile, 4 waves 2Mx2N, acc[2][4]=32 AGPR, 2 barriers/step,
// uniform gload_lds staging from pre-converted bf16, XCD-pairing swizzle),
// with only the output changed to a disjoint per-half partial store
// (R14-verified). bV dropped (softmax shift-invariant).
__global__ __launch_bounds__(256, 2) void k2_score(
    const unsigned short* __restrict__ Av,
    const unsigned short* __restrict__ W2Th,
    const float* __restrict__ qp,
    const float* __restrict__ b2,
    const float* __restrict__ V,
    float* __restrict__ scorep) {
    __shared__ unsigned short sAh[BM * BK];   // 8 KB
    __shared__ unsigned short sBh[BN * BK];   // 16 KB
    __shared__ float red[2 * BM];

    const int tid = threadIdx.x;
    const int lane = tid & 63;
    const int wid = tid >> 6;
    const int wm = wid >> 1, wn = wid & 1;    // wave tile 32x64
    const int g = lane >> 4, c16 = lane & 15;

    // XCD-pairing swizzle: bid -> wgid (bit rotation, bijective on [0,2048))
    const int bid = blockIdx.x;
    const int wgid = ((bid & 7) << 8) | (bid >> 3);
    const int m0 = (wgid >> 1) * BM;
    const int b = m0 >> 11; // m0 / T_
    const int half = wgid & 1;
    const int nt0 = half * NTP;

    // gload_lds staging mapping (per-wave, 8 rows x 8 chunks per instr)
    const int b_rl = lane >> 3;
    const int b_j = lane & 7;

    float rowpart[8];
    #pragma unroll
    for (int i = 0; i < 8; i++) rowpart[i] = 0.f;

    for (int nt = nt0; nt < nt0 + NTP; nt++) {
        f32x4 acc[2][4];
        #pragma unroll
        for (int mi = 0; mi < 2; mi++)
            #pragma unroll
            for (int ni = 0; ni < 4; ni++) {
                f32x4 z = {0.f, 0.f, 0.f, 0.f};
                acc[mi][ni] = z;
            }

        for (int kt = 0; kt < D_ / BK; kt++) {
            const int k0 = kt * BK;
            __syncthreads(); // previous compute done before LDS overwrite

            // --- B tile: 4 gload_lds/thread from W2T, source pre-swizzled
            #pragma unroll
            for (int i = 0; i < 4; i++) {
                int r = wid * 32 + i * 8 + b_rl;
                int jj = b_j ^ (r & 7);
                size_t soff = (size_t)(nt * BN + r) * D_ + k0 + jj * 8;
                gload_lds16(W2Th + soff, &sBh[(wid * 32 + i * 8) * 64]);
            }
            // --- A tile: 2 gload_lds/thread from Av, source pre-swizzled
            #pragma unroll
            for (int i = 0; i < 2; i++) {
                int r = wid * 16 + i * 8 + b_rl;
                int jj = b_j ^ (r & 7);
                size_t soff = (size_t)(m0 + r) * D_ + k0 + jj * 8;
                gload_lds16(Av + soff, &sAh[(wid * 16 + i * 8) * 64]);
            }

            __syncthreads(); // drains vmcnt (gload_lds)

            #pragma unroll
            for (int s = 0; s < 2; s++) {
                bf16x8 aH[2], bH[4];
                #pragma unroll
                for (int mi = 0; mi < 2; mi++) {
                    int r = wm * 32 + mi * 16 + c16;
                    int idx = r * 64 + (((s * 4 + g) ^ (r & 7)) << 3);
                    aH[mi] = *(const bf16x8*)&sAh[idx];
                }
                #pragma unroll
                for (int ni = 0; ni < 4; ni++) {
                    int r = wn * 64 + ni * 16 + c16;
                    int idx = r * 64 + (((s * 4 + g) ^ (r & 7)) << 3);
                    bH[ni] = *(const bf16x8*)&sBh[idx];
                }
                #pragma unroll
                for (int mi = 0; mi < 2; mi++)
                    #pragma unroll
                    for (int ni = 0; ni < 4; ni++)
                        acc[mi][ni] = __builtin_amdgcn_mfma_f32_16x16x32_bf16(aH[mi], bH[ni], acc[mi][ni], 0, 0, 0);
            }
        }

        // --- epilogue: accumulate V[n]*tanh(acc + qp + b2) into row partials
        #pragma unroll
        for (int ni = 0; ni < 4; ni++) {
            int n = nt * BN + wn * 64 + ni * 16 + c16;
            float qv = qp[b * N_ + n] + b2[n];
            float Vv = V[n];
            #pragma unroll
            for (int mi = 0; mi < 2; mi++)
                #pragma unroll
                for (int r = 0; r < 4; r++) {
                    rowpart[mi * 4 + r] += tanhf(acc[mi][ni][r] + qv) * Vv;
                }
        }
    }

    // reduce across the 16 n-lanes of each group
    #pragma unroll
    for (int i = 0; i < 8; i++) {
        float v = rowpart[i];
        v += __shfl_xor(v, 1);
        v += __shfl_xor(v, 2);
        v += __shfl_xor(v, 4);
        v += __shfl_xor(v, 8);
        rowpart[i] = v;
    }
    if (c16 == 0) {
        #pragma unroll
        for (int mi = 0; mi < 2; mi++)
            #pragma unroll
            for (int r = 0; r < 4; r++)
                red[wn * BM + wm * 32 + mi * 16 + g * 4 + r] = rowpart[mi * 4 + r];
    }
    __syncthreads();
    if (tid < BM) {
        // plain store to this half's disjoint partial buffer (no atomics)
        scorep[(size_t)half * M_ + m0 + tid] = red[tid] + red[BM + tid];
    }
}

// K3: softmax over T per batch: sums the two score partials, softmaxes,
// writes weights (d_out region written only here).
__global__ void k3_softmax(const float* __restrict__ sp,
                           float* __restrict__ sw) {
    int b = blockIdx.x;
    const float* r0 = sp + b * T_;
    const float* r1 = sp + M_ + b * T_;
    float* row = sw + b * T_;
    int tid = threadIdx.x;
    float v[8];
    float lmax = -1e30f;
    #pragma unroll
    for (int i = 0; i < 8; i++) {
        int idx = tid + i * 256;
        v[i] = r0[idx] + r1[idx];
        lmax = fmaxf(lmax, v[i]);
    }
    #pragma unroll
    for (int d = 1; d < 64; d <<= 1) lmax = fmaxf(lmax, __shfl_xor(lmax, d));
    __shared__ float sm[4], ss[4];
    if ((tid & 63) == 0) sm[tid >> 6] = lmax;
    __syncthreads();
    lmax = fmaxf(fmaxf(sm[0], sm[1]), fmaxf(sm[2], sm[3]));
    float lsum = 0.f;
    #pragma unroll
    for (int i = 0; i < 8; i++) {
        v[i] = expf(v[i] - lmax);
        lsum += v[i];
    }
    #pragma unroll
    for (int d = 1; d < 64; d <<= 1) lsum += __shfl_xor(lsum, d);
    if ((tid & 63) == 0) ss[tid >> 6] = lsum;
    __syncthreads();
    lsum = ss[0] + ss[1] + ss[2] + ss[3];
    float inv = 1.f / lsum;
    #pragma unroll
    for (int i = 0; i < 8; i++) row[tid + i * 256] = v[i] * inv;
}

// K4: context[b][d] += partial over t-slice, reading bf16 Av (half traffic).
// (atomic, ctx pre-zeroed)
__global__ void k4_context(const unsigned short* __restrict__ Av,
                           const float* __restrict__ w,
                           float* __restrict__ ctx) {
    int b = blockIdx.x;
    int dc = blockIdx.y;           // 8 chunks of 128 d
    int tc = blockIdx.z;           // 8 chunks of 256 t
    int d4 = threadIdx.x & 31;
    int th = threadIdx.x >> 5;     // 8 t-slices of 32
    const float* wrow = w + b * T_;
    int d = dc * 128 + d4 * 4;
    const unsigned short* vbase = Av + (size_t)b * T_ * D_ + d;
    float4 acc = {0.f, 0.f, 0.f, 0.f};
    int t0 = tc * 256 + th * 32;
    for (int t = t0; t < t0 + 32; t++) {
        float wt = wrow[t];
        us4 hv = *(const us4*)(vbase + (size_t)t * D_);
        acc.x += wt * __uint_as_float((unsigned)hv[0] << 16);
        acc.y += wt * __uint_as_float((unsigned)hv[1] << 16);
        acc.z += wt * __uint_as_float((unsigned)hv[2] << 16);
        acc.w += wt * __uint_as_float((unsigned)hv[3] << 16);
    }
    __shared__ float4 red4[256];
    red4[threadIdx.x] = acc;
    __syncthreads();
    if (th == 0) {
        float4 s = red4[d4];
        #pragma unroll
        for (int i = 1; i < 8; i++) {
            float4 o = red4[i * 32 + d4];
            s.x += o.x; s.y += o.y; s.z += o.z; s.w += o.w;
        }
        atomicAdd(&ctx[b * D_ + d + 0], s.x);
        atomicAdd(&ctx[b * D_ + d + 1], s.y);
        atomicAdd(&ctx[b * D_ + d + 2], s.z);
        atomicAdd(&ctx[b * D_ + d + 3], s.w);
    }
}

extern "C" void kernel_launch(void* const* d_in, const int* in_sizes, int n_in,
                              void* d_out, int out_size, void* d_ws, size_t ws_size,
                              hipStream_t stream) {
    const float* query  = (const float*)d_in[0];
    const float* values = (const float*)d_in[1];
    const float* W1     = (const float*)d_in[2];
    const float* b1     = (const float*)d_in[3];
    const float* W2     = (const float*)d_in[4];
    const float* b2     = (const float*)d_in[5];
    const float* V      = (const float*)d_in[6];
    // d_in[7] = bV: unused — softmax is shift-invariant, bV affects neither output.

    float* ctx = (float*)d_out;                 // [B, D]
    float* weights = (float*)d_out + B_ * D_;   // [B, T]: written by k3 only

    // ws: W2T (2 MB) | q_proj (128 KB) | score partials (512 KB) | Av bf16 (128 MB)
    size_t need = (size_t)N_ * D_ * sizeof(unsigned short)
                + (size_t)B_ * N_ * sizeof(float)
                + (size_t)NTSPLIT * M_ * sizeof(float)
                + (size_t)M_ * D_ * sizeof(unsigned short);
    if (ws_size < need) return;
    unsigned short* Th = (unsigned short*)d_ws;
    float* qp = (float*)(Th + (size_t)N_ * D_);
    float* scorep = qp + (size_t)B_ * N_;
    unsigned short* Av = (unsigned short*)(scorep + (size_t)NTSPLIT * M_);

    k_prep<<<3200, 256, 0, stream>>>(values, Av, W2, Th, query, W1, b1, qp);
    k2_score<<<(M_ / BM) * NTSPLIT, 256, 0, stream>>>(Av, Th, qp, b2, V, scorep);
    k3_softmax<<<B_, 256, 0, stream>>>(scorep, weights);
    hipMemsetAsync(ctx, 0, (size_t)B_ * D_ * sizeof(float), stream);
    k4_context<<<dim3(B_, 8, 8), 256, 0, stream>>>(Av, weights, ctx);
}